// Round 1
// baseline (458.109 us; speedup 1.0000x reference)
//
#include <hip/hip_runtime.h>

#define BB 128
#define TT 4096
#define LL 43
#define CC 46             // L + 3
#define CHUNK 64          // one wave per chunk
#define NC (TT / CHUNK)   // 64 chunks == 64 lanes in the per-batch finisher
#define NEGF (-1e30f)
#define L2E 1.44269504088896340736f
#define LN2 0.69314718055994530942f

// native single-instruction transcendentals (v_exp_f32 / v_log_f32, ~1 ulp)
__device__ __forceinline__ float fexp2(float x) { return __builtin_amdgcn_exp2f(x); }
__device__ __forceinline__ float flog2(float x) { return __builtin_amdgcn_logf(x); }
__device__ __forceinline__ float frcp(float x)  { return __builtin_amdgcn_rcpf(x); }

// ws layout: res[B][NC][8] floats (256 KB) | val[B] floats | cnt[B+1] ints
// Single fused kernel: per-chunk 2x2 matrices composed in LINEAR domain with
// a shared power-of-2 exponent; the LAST block to finish a batch (per-batch
// agent-scope counter) runs that batch's 64-chunk reduction in-place; the
// last batch-finisher sums val[] and stores out[0] directly. This removes
// the second kernel node and its full-grid drain (G16-safe: last-arriver
// pattern, no dispatch-order assumptions; ACQ_REL agent-scope RMWs carry
// release/acquire for the cross-XCD res/val handoff).
__global__ __launch_bounds__(64) void crf_fused(
    const float* __restrict__ lp, const float* __restrict__ dp,
    const int* __restrict__ lens, const int* __restrict__ labels,
    float* __restrict__ res, float* __restrict__ val,
    int* __restrict__ cnt, float* __restrict__ out) {
    __shared__ float tile[CHUNK * CC];   // 11776 B, contiguous (global_load_lds layout)
    __shared__ float2 pp[LL + 1];        // (p0[j], p1[j])
    __shared__ float sc[4];              // pO, s0I*L2E, s1I*L2E, (unused)

    int b = blockIdx.y, c = blockIdx.x;
    int t0 = c * CHUNK;
    int len = lens[b];
    int lane = threadIdx.x;              // 0..63
    float* r = res + (b * NC + c) * 8;

    if (t0 >= len) {   // fully masked chunk: identity, no HBM tile traffic
        if (lane == 0) {
            *(float4*)r = make_float4(0.f, NEGF, NEGF, 0.f);
            r[4] = 0.f;
        }
    } else {
        // ---- async global->LDS staging: 11 x 1024B + 512B tail ----
        {
            const float* gsrc = lp + (size_t)(b * TT + t0) * CC;   // 16B-aligned
            #pragma unroll
            for (int s = 0; s < 11; ++s) {
                const float* g = gsrc + s * 256 + lane * 4;
                float* l = tile + s * 256;               // wave-uniform base (+lane*16 implicit)
                __builtin_amdgcn_global_load_lds(
                    (const __attribute__((address_space(1))) void*)g,
                    (__attribute__((address_space(3))) void*)l, 16, 0, 0);
            }
            if (lane < 32) {                             // tail: 128 floats
                const float* g = gsrc + 11 * 256 + lane * 4;
                float* l = tile + 11 * 256;
                __builtin_amdgcn_global_load_lds(
                    (const __attribute__((address_space(1))) void*)g,
                    (__attribute__((address_space(3))) void*)l, 16, 0, 0);
            }
        }

        // ---- prep: no max-subtract (|dp|<0.1); overlaps staging drain ----
        {
            float x0 = (lane < CC) ? dp[lane] : NEGF;
            float x1 = (lane < LL + 1) ? dp[CC + lane] : NEGF;
            float e0 = fexp2(L2E * x0);          // NEGF -> 0
            float e1 = fexp2(L2E * x1);
            float s0 = e0, s1 = e1;
            #pragma unroll
            for (int m = 1; m < 64; m <<= 1) {
                s0 += __shfl_xor(s0, m);
                s1 += __shfl_xor(s1, m);
            }
            float r0 = frcp(s0), r1 = frcp(s1);
            float g0 = L2E * x0 - flog2(s0);     // log2-domain log-softmax
            float g1 = L2E * x1 - flog2(s1);
            if (lane >= 1 && lane <= LL) { pp[lane - 1].x = e0 * r0; pp[lane - 1].y = e1 * r1; }
            if (lane == 0) { sc[0] = e0 * r0; sc[2] = g1; }
            if (lane == LL + 1) sc[1] = g0;
        }

        int t = t0 + lane;
        int lab = labels[b * TT + t];   // coalesced 4B/lane; overlaps staging drain
        __syncthreads();                // 1-wave barrier: drains THIS wave's vmcnt/lgkmcnt

        // ---- per-timestep 2x2 matrix, LINEAR domain (entries in (1e-14, 1]) ----
        const float* vr = tile + lane * CC;   // 8B-aligned (46 floats/row)
        float m00, m01, m10, m11, tok;
        {
            const float2* vr2 = (const float2*)vr;
            float2 c01 = vr2[0];                 // cols 0,1
            float2 c23 = vr2[1];                 // cols 2,3
            tok = vr[lab];                       // natural-log value for numerator
            float w1 = fexp2(L2E * c01.y);
            float v2s = L2E * c23.x;
            float dot0 = sc[0] * w1;             // pO * P(col1)
            float dot1 = 0.f;
            {
                float w = fexp2(L2E * c23.y);    // label j=0
                float2 p = pp[0];
                dot0 = fmaf(p.x, w, dot0);
                dot1 = fmaf(p.y, w, dot1);
            }
            #pragma unroll
            for (int k = 2; k <= 22; ++k) {      // cols 2k,2k+1 -> labels j=2k-3,2k-2
                float2 v = vr2[k];
                float wa = fexp2(L2E * v.x), wb = fexp2(L2E * v.y);
                float2 pa = pp[2 * k - 3], pb = pp[2 * k - 2];
                dot0 = fmaf(pa.x, wa, dot0); dot1 = fmaf(pa.y, wa, dot1);
                dot0 = fmaf(pb.x, wb, dot0); dot1 = fmaf(pb.y, wb, dot1);
            }
            m00 = dot0;                          // linear entries
            m01 = dot1;
            m10 = fexp2(sc[1] + v2s);
            m11 = fexp2(sc[2] + v2s);
        }
        int ie = 0;                              // shared power-of-2 exponent
        if (t >= len) { m00 = 1.f; m01 = 0.f; m10 = 0.f; m11 = 1.f; tok = 0.f; }

        // ---- xor-tree: linear 2x2 matmul; renorm every 2 levels (range-safe:
        // two unrenormalized levels stay > 2^-100; <2^-90-relative terms are
        // below f32 epsilon of the result anyway) ----
        #pragma unroll
        for (int lev = 0; lev < 6; ++lev) {
            int m = 1 << lev;
            float p00 = __shfl_xor(m00, m), p01 = __shfl_xor(m01, m);
            float p10 = __shfl_xor(m10, m), p11 = __shfl_xor(m11, m);
            int   pe  = __shfl_xor(ie, m);
            float ptk = __shfl_xor(tok, m);
            bool up = (lane & m) != 0;           // my segment is LATER in time
            float a00 = up ? m00 : p00, a01 = up ? m01 : p01;   // A = later
            float a10 = up ? m10 : p10, a11 = up ? m11 : p11;
            float b00 = up ? p00 : m00, b01 = up ? p01 : m01;   // B = earlier
            float b10 = up ? p10 : m10, b11 = up ? p11 : m11;
            float n00 = fmaf(a01, b10, a00 * b00);
            float n01 = fmaf(a01, b11, a00 * b01);
            float n10 = fmaf(a11, b10, a10 * b00);
            float n11 = fmaf(a11, b11, a10 * b01);
            ie += pe;
            tok += ptk;
            if (lev & 1) {                       // renorm after levels 1,3,5
                float mx = fmaxf(fmaxf(n00, n01), fmaxf(n10, n11));   // > 0 always
                unsigned bi = __float_as_uint(mx) >> 23;              // biased exponent
                float scl = __uint_as_float((254u - bi) << 23);       // 2^(127-bi)
                n00 *= scl; n01 *= scl; n10 *= scl; n11 *= scl;
                ie += (int)bi - 127;
            }
            m00 = n00; m01 = n01; m10 = n10; m11 = n11;
        }
        if (lane == 0) {                         // back to log2 domain
            float fe = (float)ie;
            float4 v = make_float4(flog2(m00) + fe, flog2(m01) + fe,
                                   flog2(m10) + fe, flog2(m11) + fe);
            *(float4*)r = v;
            r[4] = tok;
        }
    }

    // ---- completion protocol: last arriver for batch b reduces batch b ----
    // ACQ_REL agent-scope RMW: release orders this block's res stores before
    // the counter bump; acquire on reading NC-1 makes all 64 blocks' res rows
    // visible (RMW chain preserves the release sequence across XCDs).
    int old = 0;
    if (lane == 0)
        old = __hip_atomic_fetch_add(&cnt[b], 1, __ATOMIC_ACQ_REL,
                                     __HIP_MEMORY_SCOPE_AGENT);
    old = __shfl(old, 0);
    if (old == NC - 1) {
        __threadfence();                         // belt-and-suspenders acquire

        // sfin (log2 domain); no max-subtract (|dp|<0.1)
        float sfin2;
        {
            float x0 = (lane < CC) ? dp[lane] : NEGF;
            float e0 = fexp2(L2E * x0);
            float s0 = e0;
            #pragma unroll
            for (int m = 1; m < 64; m <<= 1) s0 += __shfl_xor(s0, m);
            float g0 = L2E * x0 - flog2(s0);
            sfin2 = __shfl(g0, LL + 2);          // broadcast lane L+2's log-softmax
        }

        // load chunk matrix (log2 domain), convert to linear + exponent
        const float* rr = res + (b * NC + lane) * 8;
        float4 rv = *(const float4*)rr;          // 32B-aligned, fresh from L2
        float tk = rr[4];
        float rm = fmaxf(fmaxf(rv.x, rv.y), fmaxf(rv.z, rv.w));
        int ie = (int)__builtin_floorf(rm);      // per-matrix exponent (identity -> 0)
        float fe = (float)ie;
        float m00 = fexp2(rv.x - fe), m01 = fexp2(rv.y - fe);
        float m10 = fexp2(rv.z - fe), m11 = fexp2(rv.w - fe);   // NEGF -> 0

        // xor-tree over 64 chunks: linear 2x2 matmul + block-exponent renorm
        #pragma unroll
        for (int m = 1; m < 64; m <<= 1) {
            float p00 = __shfl_xor(m00, m), p01 = __shfl_xor(m01, m);
            float p10 = __shfl_xor(m10, m), p11 = __shfl_xor(m11, m);
            int   pe  = __shfl_xor(ie, m);
            float ptk = __shfl_xor(tk, m);
            bool up = (lane & m) != 0;           // my chunk is LATER in time
            float a00 = up ? m00 : p00, a01 = up ? m01 : p01;   // A = later
            float a10 = up ? m10 : p10, a11 = up ? m11 : p11;
            float b00 = up ? p00 : m00, b01 = up ? p01 : m01;   // B = earlier
            float b10 = up ? p10 : m10, b11 = up ? p11 : m11;
            float n00 = fmaf(a01, b10, a00 * b00);
            float n01 = fmaf(a01, b11, a00 * b01);
            float n10 = fmaf(a11, b10, a10 * b00);
            float n11 = fmaf(a11, b11, a10 * b01);
            float mx = fmaxf(fmaxf(n00, n01), fmaxf(n10, n11));
            unsigned bi = __float_as_uint(mx) >> 23;
            float scl = __uint_as_float((254u - bi) << 23);
            m00 = n00 * scl; m01 = n01 * scl;
            m10 = n10 * scl; m11 = n11 * scl;
            ie = ie + pe + (int)bi - 127;
            tk += ptk;
        }

        if (lane == 0) {
            // alpha_final = M_total o (1, -inf): a0 = m00 * 2^ie (linear)
            float den2 = flog2(m00) + (float)ie + sfin2;   // log2 domain
            val[b] = tk - den2 * LN2;
        }

        // last batch-finisher sums the 128 per-batch values, stores out[0]
        int g = 0;
        if (lane == 0)
            g = __hip_atomic_fetch_add(&cnt[BB], 1, __ATOMIC_ACQ_REL,
                                       __HIP_MEMORY_SCOPE_AGENT);
        g = __shfl(g, 0);
        if (g == BB - 1) {
            __threadfence();
            float v = val[lane] + val[lane + 64];   // BB == 128, 64 lanes
            #pragma unroll
            for (int m = 1; m < 64; m <<= 1) v += __shfl_xor(v, m);
            if (lane == 0) out[0] = v;              // plain store: no zeroing needed
        }
    }
}

extern "C" void kernel_launch(void* const* d_in, const int* in_sizes, int n_in,
                              void* d_out, int out_size, void* d_ws, size_t ws_size,
                              hipStream_t stream) {
    const float* lp = (const float*)d_in[0];      // (B,T,C) f32
    const float* dp = (const float*)d_in[1];      // (2L+4,) f32
    const int* lens = (const int*)d_in[2];        // (B,) i32
    const int* labels = (const int*)d_in[3];      // (B,T) i32
    float* out = (float*)d_out;
    float* res = (float*)d_ws;                    // B*NC*8 floats = 256 KB
    float* val = res + BB * NC * 8;               // B floats
    int* cnt = (int*)(val + BB);                  // B+1 ints (per-batch + global)

    // counters must be zeroed each iteration (ws is re-poisoned); 516 B,
    // graph-capturable, stream-ordered before the kernel's atomics
    hipMemsetAsync(cnt, 0, (BB + 1) * sizeof(int), stream);
    hipLaunchKernelGGL(crf_fused, dim3(NC, BB), dim3(64), 0, stream,
                       lp, dp, lens, labels, res, val, cnt, out);
}

// Round 2
// 168.559 us; speedup vs baseline: 2.7178x; 2.7178x over previous
//
#include <hip/hip_runtime.h>

#define BB 128
#define TT 4096
#define LL 43
#define CC 46             // L + 3
#define CHUNK 64          // one wave per chunk
#define NC (TT / CHUNK)   // 64 chunks == 64 lanes in the per-batch finisher
#define NEGF (-1e30f)
#define L2E 1.44269504088896340736f
#define LN2 0.69314718055994530942f

// native single-instruction transcendentals (v_exp_f32 / v_log_f32, ~1 ulp)
__device__ __forceinline__ float fexp2(float x) { return __builtin_amdgcn_exp2f(x); }
__device__ __forceinline__ float flog2(float x) { return __builtin_amdgcn_logf(x); }
__device__ __forceinline__ float frcp(float x)  { return __builtin_amdgcn_rcpf(x); }

// Agent-scope RELAXED atomics: compile to single global_load/store with sc1
// (coherent at the IF$ point, bypassing the non-coherent per-XCD L2) and NO
// buffer_wbl2 / buffer_inv. Round-1's ACQ_REL protocol emitted 8192 full-L2
// writebacks + invalidates -> 365us all-stall (1.3% VALUBusy, 1.3% HBM).
#define AST(p, v) __hip_atomic_store((p), (v), __ATOMIC_RELAXED, __HIP_MEMORY_SCOPE_AGENT)
#define ALD(p)    __hip_atomic_load((p), __ATOMIC_RELAXED, __HIP_MEMORY_SCOPE_AGENT)

__device__ __forceinline__ unsigned long long pack2(float a, float b) {
    return ((unsigned long long)__float_as_uint(b) << 32) | (unsigned long long)__float_as_uint(a);
}

// ws layout: res[B][NC][8] floats (256 KB) | val[B] floats | cnt[B+1] ints
// Single fused kernel. Chunk result handoff format (LINEAR + exponent, no
// log2 round trip): r[0..3]=m00,m01,m10,m11 (max entry in [1,2)), r[4]=tok,
// r[5]=ie (bitcast int). Last-arriver per batch reduces the 64 chunks; last
// batch-finisher sums val[] and stores out[0]. G16-safe: no dispatch-order
// assumptions; ordering = sc1 stores + s_waitcnt vmcnt(0) + relaxed RMW
// (store-ack at the coherence point IS the release; no cache maintenance).
__global__ __launch_bounds__(64) void crf_fused(
    const float* __restrict__ lp, const float* __restrict__ dp,
    const int* __restrict__ lens, const int* __restrict__ labels,
    float* __restrict__ res, float* __restrict__ val,
    int* __restrict__ cnt, float* __restrict__ out) {
    __shared__ float tile[CHUNK * CC];   // 11776 B, contiguous (global_load_lds layout)
    __shared__ float2 pp[LL + 1];        // (p0[j], p1[j])
    __shared__ float sc[4];              // pO, s0I*L2E, s1I*L2E, (unused)

    int b = blockIdx.y, c = blockIdx.x;
    int t0 = c * CHUNK;
    int len = lens[b];
    int lane = threadIdx.x;              // 0..63

    float m00, m01, m10, m11, tok;
    int ie = 0;                          // shared power-of-2 exponent

    if (t0 >= len) {   // fully masked chunk: identity, no HBM tile traffic
        m00 = 1.f; m01 = 0.f; m10 = 0.f; m11 = 1.f; tok = 0.f;
    } else {
        // ---- async global->LDS staging: 11 x 1024B + 512B tail ----
        {
            const float* gsrc = lp + (size_t)(b * TT + t0) * CC;   // 16B-aligned
            #pragma unroll
            for (int s = 0; s < 11; ++s) {
                const float* g = gsrc + s * 256 + lane * 4;
                float* l = tile + s * 256;               // wave-uniform base (+lane*16 implicit)
                __builtin_amdgcn_global_load_lds(
                    (const __attribute__((address_space(1))) void*)g,
                    (__attribute__((address_space(3))) void*)l, 16, 0, 0);
            }
            if (lane < 32) {                             // tail: 128 floats
                const float* g = gsrc + 11 * 256 + lane * 4;
                float* l = tile + 11 * 256;
                __builtin_amdgcn_global_load_lds(
                    (const __attribute__((address_space(1))) void*)g,
                    (__attribute__((address_space(3))) void*)l, 16, 0, 0);
            }
        }

        // ---- prep: no max-subtract (|dp|<0.1); overlaps staging drain ----
        {
            float x0 = (lane < CC) ? dp[lane] : NEGF;
            float x1 = (lane < LL + 1) ? dp[CC + lane] : NEGF;
            float e0 = fexp2(L2E * x0);          // NEGF -> 0
            float e1 = fexp2(L2E * x1);
            float s0 = e0, s1 = e1;
            #pragma unroll
            for (int m = 1; m < 64; m <<= 1) {
                s0 += __shfl_xor(s0, m);
                s1 += __shfl_xor(s1, m);
            }
            float r0 = frcp(s0), r1 = frcp(s1);
            float g0 = L2E * x0 - flog2(s0);     // log2-domain log-softmax
            float g1 = L2E * x1 - flog2(s1);
            if (lane >= 1 && lane <= LL) { pp[lane - 1].x = e0 * r0; pp[lane - 1].y = e1 * r1; }
            if (lane == 0) { sc[0] = e0 * r0; sc[2] = g1; }
            if (lane == LL + 1) sc[1] = g0;
        }

        int t = t0 + lane;
        int lab = labels[b * TT + t];   // coalesced 4B/lane; overlaps staging drain
        __syncthreads();                // 1-wave barrier: drains THIS wave's vmcnt/lgkmcnt

        // ---- per-timestep 2x2 matrix, LINEAR domain (entries in (1e-14, 1]) ----
        const float* vr = tile + lane * CC;   // 8B-aligned (46 floats/row)
        {
            const float2* vr2 = (const float2*)vr;
            float2 c01 = vr2[0];                 // cols 0,1
            float2 c23 = vr2[1];                 // cols 2,3
            tok = vr[lab];                       // natural-log value for numerator
            float w1 = fexp2(L2E * c01.y);
            float v2s = L2E * c23.x;
            float dot0 = sc[0] * w1;             // pO * P(col1)
            float dot1 = 0.f;
            {
                float w = fexp2(L2E * c23.y);    // label j=0
                float2 p = pp[0];
                dot0 = fmaf(p.x, w, dot0);
                dot1 = fmaf(p.y, w, dot1);
            }
            #pragma unroll
            for (int k = 2; k <= 22; ++k) {      // cols 2k,2k+1 -> labels j=2k-3,2k-2
                float2 v = vr2[k];
                float wa = fexp2(L2E * v.x), wb = fexp2(L2E * v.y);
                float2 pa = pp[2 * k - 3], pb = pp[2 * k - 2];
                dot0 = fmaf(pa.x, wa, dot0); dot1 = fmaf(pa.y, wa, dot1);
                dot0 = fmaf(pb.x, wb, dot0); dot1 = fmaf(pb.y, wb, dot1);
            }
            m00 = dot0;                          // linear entries
            m01 = dot1;
            m10 = fexp2(sc[1] + v2s);
            m11 = fexp2(sc[2] + v2s);
        }
        if (t >= len) { m00 = 1.f; m01 = 0.f; m10 = 0.f; m11 = 1.f; tok = 0.f; }

        // ---- xor-tree: linear 2x2 matmul; renorm every 2 levels (range-safe:
        // two unrenormalized levels stay > 2^-100; <2^-90-relative terms are
        // below f32 epsilon of the result anyway) ----
        #pragma unroll
        for (int lev = 0; lev < 6; ++lev) {
            int m = 1 << lev;
            float p00 = __shfl_xor(m00, m), p01 = __shfl_xor(m01, m);
            float p10 = __shfl_xor(m10, m), p11 = __shfl_xor(m11, m);
            int   pe  = __shfl_xor(ie, m);
            float ptk = __shfl_xor(tok, m);
            bool up = (lane & m) != 0;           // my segment is LATER in time
            float a00 = up ? m00 : p00, a01 = up ? m01 : p01;   // A = later
            float a10 = up ? m10 : p10, a11 = up ? m11 : p11;
            float b00 = up ? p00 : m00, b01 = up ? p01 : m01;   // B = earlier
            float b10 = up ? p10 : m10, b11 = up ? p11 : m11;
            float n00 = fmaf(a01, b10, a00 * b00);
            float n01 = fmaf(a01, b11, a00 * b01);
            float n10 = fmaf(a11, b10, a10 * b00);
            float n11 = fmaf(a11, b11, a10 * b01);
            ie += pe;
            tok += ptk;
            if (lev & 1) {                       // renorm after levels 1,3,5
                float mx = fmaxf(fmaxf(n00, n01), fmaxf(n10, n11));   // > 0 always
                unsigned bi = __float_as_uint(mx) >> 23;              // biased exponent
                float scl = __uint_as_float((254u - bi) << 23);       // 2^(127-bi)
                n00 *= scl; n01 *= scl; n10 *= scl; n11 *= scl;
                ie += (int)bi - 127;
            }
            m00 = n00; m01 = n01; m10 = n10; m11 = n11;
        }
    }

    // ---- handoff: sc1 stores (packed 64-bit x3), waitcnt, relaxed RMW ----
    float* r = res + (b * NC + c) * 8;           // 32B-aligned
    if (lane == 0) {
        AST((unsigned long long*)(r + 0), pack2(m00, m01));
        AST((unsigned long long*)(r + 2), pack2(m10, m11));
        AST((unsigned long long*)(r + 4), pack2(tok, __int_as_float(ie)));
    }
    // store-ack from the coherence point IS the release for sc1 data
    asm volatile("s_waitcnt vmcnt(0)" ::: "memory");
    int old = 0;
    if (lane == 0)
        old = __hip_atomic_fetch_add(&cnt[b], 1, __ATOMIC_RELAXED,
                                     __HIP_MEMORY_SCOPE_AGENT);
    old = __shfl(old, 0);

    if (old == NC - 1) {   // last arriver for batch b: reduce 64 chunk matrices
        // sfin (log2 domain); no max-subtract (|dp|<0.1)
        float sfin2;
        {
            float x0 = (lane < CC) ? dp[lane] : NEGF;
            float e0 = fexp2(L2E * x0);
            float s0 = e0;
            #pragma unroll
            for (int m = 1; m < 64; m <<= 1) s0 += __shfl_xor(s0, m);
            float g0 = L2E * x0 - flog2(s0);
            sfin2 = __shfl(g0, LL + 2);          // broadcast lane L+2's log-softmax
        }

        // load chunk matrix via sc1 (bypasses possibly-stale local L2)
        float* rr = res + (b * NC + lane) * 8;
        unsigned long long w0 = ALD((unsigned long long*)(rr + 0));
        unsigned long long w1 = ALD((unsigned long long*)(rr + 2));
        unsigned long long w2 = ALD((unsigned long long*)(rr + 4));
        float f00 = __uint_as_float((unsigned)w0), f01 = __uint_as_float((unsigned)(w0 >> 32));
        float f10 = __uint_as_float((unsigned)w1), f11 = __uint_as_float((unsigned)(w1 >> 32));
        float tk  = __uint_as_float((unsigned)w2);
        int   ee  = (int)(unsigned)(w2 >> 32);   // bit pattern of ie

        // xor-tree over 64 chunks: linear 2x2 matmul + per-level renorm
        #pragma unroll
        for (int m = 1; m < 64; m <<= 1) {
            float p00 = __shfl_xor(f00, m), p01 = __shfl_xor(f01, m);
            float p10 = __shfl_xor(f10, m), p11 = __shfl_xor(f11, m);
            int   pe  = __shfl_xor(ee, m);
            float ptk = __shfl_xor(tk, m);
            bool up = (lane & m) != 0;           // my chunk is LATER in time
            float a00 = up ? f00 : p00, a01 = up ? f01 : p01;   // A = later
            float a10 = up ? f10 : p10, a11 = up ? f11 : p11;
            float b00 = up ? p00 : f00, b01 = up ? p01 : f01;   // B = earlier
            float b10 = up ? p10 : f10, b11 = up ? p11 : f11;
            float n00 = fmaf(a01, b10, a00 * b00);
            float n01 = fmaf(a01, b11, a00 * b01);
            float n10 = fmaf(a11, b10, a10 * b00);
            float n11 = fmaf(a11, b11, a10 * b01);
            float mx = fmaxf(fmaxf(n00, n01), fmaxf(n10, n11));
            unsigned bi = __float_as_uint(mx) >> 23;
            float scl = __uint_as_float((254u - bi) << 23);
            f00 = n00 * scl; f01 = n01 * scl;
            f10 = n10 * scl; f11 = n11 * scl;
            ee = ee + pe + (int)bi - 127;
            tk += ptk;
        }

        if (lane == 0) {
            // alpha_final = M_total o (1, -inf): a0 = f00 * 2^ee (linear)
            float den2 = flog2(f00) + (float)ee + sfin2;   // log2 domain
            AST(&val[b], tk - den2 * LN2);
        }
        asm volatile("s_waitcnt vmcnt(0)" ::: "memory");
        int g = 0;
        if (lane == 0)
            g = __hip_atomic_fetch_add(&cnt[BB], 1, __ATOMIC_RELAXED,
                                       __HIP_MEMORY_SCOPE_AGENT);
        g = __shfl(g, 0);
        if (g == BB - 1) {   // last batch-finisher: sum 128 vals, store out
            float v = ALD(&val[lane]) + ALD(&val[lane + 64]);   // BB == 128
            #pragma unroll
            for (int m = 1; m < 64; m <<= 1) v += __shfl_xor(v, m);
            if (lane == 0) out[0] = v;   // host-visible via end-of-kernel flush
        }
    }
}

extern "C" void kernel_launch(void* const* d_in, const int* in_sizes, int n_in,
                              void* d_out, int out_size, void* d_ws, size_t ws_size,
                              hipStream_t stream) {
    const float* lp = (const float*)d_in[0];      // (B,T,C) f32
    const float* dp = (const float*)d_in[1];      // (2L+4,) f32
    const int* lens = (const int*)d_in[2];        // (B,) i32
    const int* labels = (const int*)d_in[3];      // (B,T) i32
    float* out = (float*)d_out;
    float* res = (float*)d_ws;                    // B*NC*8 floats = 256 KB
    float* val = res + BB * NC * 8;               // B floats
    int* cnt = (int*)(val + BB);                  // B+1 ints (per-batch + global)

    // counters zeroed each iteration (ws is re-poisoned); 516 B, stream-ordered
    hipMemsetAsync(cnt, 0, (BB + 1) * sizeof(int), stream);
    hipLaunchKernelGGL(crf_fused, dim3(NC, BB), dim3(64), 0, stream,
                       lp, dp, lens, labels, res, val, cnt, out);
}

// Round 3
// 148.036 us; speedup vs baseline: 3.0946x; 1.1386x over previous
//
#include <hip/hip_runtime.h>

#define BB 128
#define TT 4096
#define LL 43
#define CC 46             // L + 3
#define CHUNK 64          // one wave per chunk
#define NC (TT / CHUNK)   // 64 chunks == 64 lanes in crf_final
#define NEGF (-1e30f)
#define L2E 1.44269504088896340736f
#define LN2 0.69314718055994530942f

// native single-instruction transcendentals (v_exp_f32 / v_log_f32, ~1 ulp)
__device__ __forceinline__ float fexp2(float x) { return __builtin_amdgcn_exp2f(x); }
__device__ __forceinline__ float flog2(float x) { return __builtin_amdgcn_logf(x); }
__device__ __forceinline__ float frcp(float x)  { return __builtin_amdgcn_rcpf(x); }

// ws layout: res[B][NC][8] floats (256 KB)
// Two-kernel structure (measured best): fused single-kernel variants cost
// MORE than the one dispatch boundary they remove -- r1: per-block ACQ_REL
// emitted 8192 L2 wbl2/inv pairs (365us all-stall); r2: sc1+waitcnt+RMW
// tail ~1.5us dead time per block while holding a residency slot, plus
// memset dispatch (+20us net). Kernel boundary = free device-scope fence.
// One wave per block. Chunk matrices are composed in LINEAR domain with a
// shared per-matrix power-of-2 exponent (renormalized every 2 levels).
// NOTE: den_params = 0.01*N(0,1) -> |x|<0.1, so softmax needs NO
// max-subtraction (exp2 range-safe); NEGF pad lanes give exp2->0.
__global__ __launch_bounds__(64) void crf_chunk(
    const float* __restrict__ lp, const float* __restrict__ dp,
    const int* __restrict__ lens, const int* __restrict__ labels,
    float* __restrict__ res, float* __restrict__ out) {
    __shared__ float tile[CHUNK * CC];   // 11776 B, contiguous (global_load_lds layout)
    __shared__ float2 pp[LL + 1];        // (p0[j], p1[j])
    __shared__ float sc[4];              // pO, s0I*L2E, s1I*L2E, (unused)

    int b = blockIdx.y, c = blockIdx.x;
    int t0 = c * CHUNK;
    int len = lens[b];
    int lane = threadIdx.x;              // 0..63

    // zero the output accumulator (crf_final's atomicAdds run after the
    // kernel boundary, so this is race-free)
    if (b == 0 && c == 0 && lane == 0) out[0] = 0.f;

    // fully masked chunk: exit with NO store; crf_final synthesizes the
    // identity for these lanes from lens[b] (never reads poisoned res rows)
    if (t0 >= len) return;

    // ---- async global->LDS staging: 11 x 1024B + 512B tail, fire-and-forget ----
    {
        const float* gsrc = lp + (size_t)(b * TT + t0) * CC;   // 16B-aligned
        #pragma unroll
        for (int s = 0; s < 11; ++s) {
            const float* g = gsrc + s * 256 + lane * 4;
            float* l = tile + s * 256;                   // wave-uniform base (+lane*16 implicit)
            __builtin_amdgcn_global_load_lds(
                (const __attribute__((address_space(1))) void*)g,
                (__attribute__((address_space(3))) void*)l, 16, 0, 0);
        }
        if (lane < 32) {                                 // tail: 128 floats
            const float* g = gsrc + 11 * 256 + lane * 4;
            float* l = tile + 11 * 256;
            __builtin_amdgcn_global_load_lds(
                (const __attribute__((address_space(1))) void*)g,
                (__attribute__((address_space(3))) void*)l, 16, 0, 0);
        }
    }

    // ---- prep: no max-subtract (|dp|<0.1); overlaps staging drain ----
    {
        float x0 = (lane < CC) ? dp[lane] : NEGF;
        float x1 = (lane < LL + 1) ? dp[CC + lane] : NEGF;
        float e0 = fexp2(L2E * x0);          // NEGF -> 0
        float e1 = fexp2(L2E * x1);
        float s0 = e0, s1 = e1;
        #pragma unroll
        for (int m = 1; m < 64; m <<= 1) {
            s0 += __shfl_xor(s0, m);
            s1 += __shfl_xor(s1, m);
        }
        float r0 = frcp(s0), r1 = frcp(s1);
        float g0 = L2E * x0 - flog2(s0);     // log2-domain log-softmax
        float g1 = L2E * x1 - flog2(s1);
        if (lane >= 1 && lane <= LL) { pp[lane - 1].x = e0 * r0; pp[lane - 1].y = e1 * r1; }
        if (lane == 0) { sc[0] = e0 * r0; sc[2] = g1; }
        if (lane == LL + 1) sc[1] = g0;
    }

    int t = t0 + lane;
    int lab = labels[b * TT + t];   // coalesced 4B/lane; overlaps staging drain
    __syncthreads();                // 1-wave barrier: drains THIS wave's vmcnt/lgkmcnt

    // ---- per-timestep 2x2 matrix, LINEAR domain (entries in (1e-14, 1]) ----
    const float* vr = tile + lane * CC;   // 8B-aligned (46 floats/row)
    float m00, m01, m10, m11, tok;
    {
        const float2* vr2 = (const float2*)vr;
        float2 c01 = vr2[0];                 // cols 0,1
        float2 c23 = vr2[1];                 // cols 2,3
        tok = vr[lab];                       // natural-log value for numerator
        float w1 = fexp2(L2E * c01.y);
        float v2s = L2E * c23.x;
        float dot0 = sc[0] * w1;             // pO * P(col1)
        float dot1 = 0.f;
        {
            float w = fexp2(L2E * c23.y);    // label j=0
            float2 p = pp[0];
            dot0 = fmaf(p.x, w, dot0);
            dot1 = fmaf(p.y, w, dot1);
        }
        #pragma unroll
        for (int k = 2; k <= 22; ++k) {      // cols 2k,2k+1 -> labels j=2k-3,2k-2
            float2 v = vr2[k];
            float wa = fexp2(L2E * v.x), wb = fexp2(L2E * v.y);
            float2 pa = pp[2 * k - 3], pb = pp[2 * k - 2];
            dot0 = fmaf(pa.x, wa, dot0); dot1 = fmaf(pa.y, wa, dot1);
            dot0 = fmaf(pb.x, wb, dot0); dot1 = fmaf(pb.y, wb, dot1);
        }
        m00 = dot0;                          // linear entries
        m01 = dot1;
        m10 = fexp2(sc[1] + v2s);
        m11 = fexp2(sc[2] + v2s);
    }
    int ie = 0;                              // shared power-of-2 exponent
    if (t >= len) { m00 = 1.f; m01 = 0.f; m10 = 0.f; m11 = 1.f; tok = 0.f; }

    // ---- xor-tree: linear 2x2 matmul; renorm every 2 levels (range-safe:
    // two unrenormalized levels stay > 2^-100; <2^-90-relative terms are
    // below f32 epsilon of the result anyway) ----
    #pragma unroll
    for (int lev = 0; lev < 6; ++lev) {
        int m = 1 << lev;
        float p00 = __shfl_xor(m00, m), p01 = __shfl_xor(m01, m);
        float p10 = __shfl_xor(m10, m), p11 = __shfl_xor(m11, m);
        int   pe  = __shfl_xor(ie, m);
        float ptk = __shfl_xor(tok, m);
        bool up = (lane & m) != 0;           // my segment is LATER in time
        float a00 = up ? m00 : p00, a01 = up ? m01 : p01;   // A = later
        float a10 = up ? m10 : p10, a11 = up ? m11 : p11;
        float b00 = up ? p00 : m00, b01 = up ? p01 : m01;   // B = earlier
        float b10 = up ? p10 : m10, b11 = up ? p11 : m11;
        float n00 = fmaf(a01, b10, a00 * b00);
        float n01 = fmaf(a01, b11, a00 * b01);
        float n10 = fmaf(a11, b10, a10 * b00);
        float n11 = fmaf(a11, b11, a10 * b01);
        ie += pe;
        tok += ptk;
        if (lev & 1) {                       // renorm after levels 1,3,5
            float mx = fmaxf(fmaxf(n00, n01), fmaxf(n10, n11));   // > 0 always
            unsigned bi = __float_as_uint(mx) >> 23;              // biased exponent
            float scl = __uint_as_float((254u - bi) << 23);       // 2^(127-bi)
            n00 *= scl; n01 *= scl; n10 *= scl; n11 *= scl;
            ie += (int)bi - 127;
        }
        m00 = n00; m01 = n01; m10 = n10; m11 = n11;
    }
    if (lane == 0) {                         // back to log2 domain
        float* r = res + (b * NC + c) * 8;
        float fe = (float)ie;
        float4 v = make_float4(flog2(m00) + fe, flog2(m01) + fe,
                               flog2(m10) + fe, flog2(m11) + fe);
        *(float4*)r = v;
        r[4] = tok;
    }
}

// One wave per batch element: lane c holds chunk c's matrix (NC==64 lanes),
// composed by the same linear-domain xor-tree. 128 one-shot atomicAdds
// into out (zeroed by crf_chunk) -- no serialized RMW chain.
__global__ __launch_bounds__(256) void crf_final(
    const float* __restrict__ dp, const int* __restrict__ lens,
    const float* __restrict__ res, float* __restrict__ out) {
    int wv = threadIdx.x >> 6, lane = threadIdx.x & 63;
    int b = blockIdx.x * 4 + wv;
    int len = lens[b];

    // sfin (log2 domain), recomputed per wave; no max-subtract (|dp|<0.1)
    float sfin2;
    {
        float x0 = (lane < CC) ? dp[lane] : NEGF;
        float e0 = fexp2(L2E * x0);
        float s0 = e0;
        #pragma unroll
        for (int m = 1; m < 64; m <<= 1) s0 += __shfl_xor(s0, m);
        float g0 = L2E * x0 - flog2(s0);
        sfin2 = __shfl(g0, LL + 2);          // broadcast lane L+2's log-softmax
    }

    // load chunk matrix c (log2 domain) if active, else identity (masked
    // chunks never stored -- their res rows are poison, don't touch them)
    float m00, m01, m10, m11, tok;
    int ie;
    if (lane * CHUNK < len) {
        const float* r = res + (b * NC + lane) * 8;
        float4 rv = *(const float4*)r;           // 32B-aligned
        tok = r[4];
        float rm = fmaxf(fmaxf(rv.x, rv.y), fmaxf(rv.z, rv.w));
        ie = (int)__builtin_floorf(rm);          // per-matrix exponent
        float fe = (float)ie;
        m00 = fexp2(rv.x - fe); m01 = fexp2(rv.y - fe);
        m10 = fexp2(rv.z - fe); m11 = fexp2(rv.w - fe);
    } else {
        m00 = 1.f; m01 = 0.f; m10 = 0.f; m11 = 1.f; tok = 0.f; ie = 0;
    }

    // xor-tree: linear 2x2 matmul + block-exponent renorm per level
    #pragma unroll
    for (int m = 1; m < 64; m <<= 1) {
        float p00 = __shfl_xor(m00, m), p01 = __shfl_xor(m01, m);
        float p10 = __shfl_xor(m10, m), p11 = __shfl_xor(m11, m);
        int   pe  = __shfl_xor(ie, m);
        float ptk = __shfl_xor(tok, m);
        bool up = (lane & m) != 0;           // my chunk is LATER in time
        float a00 = up ? m00 : p00, a01 = up ? m01 : p01;   // A = later
        float a10 = up ? m10 : p10, a11 = up ? m11 : p11;
        float b00 = up ? p00 : m00, b01 = up ? p01 : m01;   // B = earlier
        float b10 = up ? p10 : m10, b11 = up ? p11 : m11;
        float n00 = fmaf(a01, b10, a00 * b00);
        float n01 = fmaf(a01, b11, a00 * b01);
        float n10 = fmaf(a11, b10, a10 * b00);
        float n11 = fmaf(a11, b11, a10 * b01);
        float mx = fmaxf(fmaxf(n00, n01), fmaxf(n10, n11));
        unsigned bi = __float_as_uint(mx) >> 23;
        float scl = __uint_as_float((254u - bi) << 23);
        m00 = n00 * scl; m01 = n01 * scl;
        m10 = n10 * scl; m11 = n11 * scl;
        ie = ie + pe + (int)bi - 127;
        tok += ptk;
    }
    if (lane == 0) {
        // alpha_final = M_total o (1, -inf): a0 = m00 * 2^ie (linear)
        float den2 = flog2(m00) + (float)ie + sfin2;   // log2 domain
        float val = tok - den2 * LN2;
        atomicAdd(out, val);                 // 128 one-shot adds, out pre-zeroed
    }
}

extern "C" void kernel_launch(void* const* d_in, const int* in_sizes, int n_in,
                              void* d_out, int out_size, void* d_ws, size_t ws_size,
                              hipStream_t stream) {
    const float* lp = (const float*)d_in[0];      // (B,T,C) f32
    const float* dp = (const float*)d_in[1];      // (2L+4,) f32
    const int* lens = (const int*)d_in[2];        // (B,) i32
    const int* labels = (const int*)d_in[3];      // (B,T) i32
    float* out = (float*)d_out;
    float* res = (float*)d_ws;                    // B*NC*8 floats = 256 KB

    hipLaunchKernelGGL(crf_chunk, dim3(NC, BB), dim3(64), 0, stream,
                       lp, dp, lens, labels, res, out);
    hipLaunchKernelGGL(crf_final, dim3(BB / 4), dim3(256), 0, stream,
                       dp, lens, res, out);
}